// Round 17
// baseline (223.549 us; speedup 1.0000x reference)
//
#include <hip/hip_runtime.h>
#include <math.h>

// Problem constants
#define Bsz 64
#define Nn 512
#define Ff 128
#define Hh 256
#define OUTD 6
#define MTOT (Bsz * Nn)   // 32768

typedef __bf16 bf16x8 __attribute__((ext_vector_type(8)));
typedef float f32x4 __attribute__((ext_vector_type(4)));
typedef int int4v __attribute__((ext_vector_type(4)));
typedef unsigned short ushort4v __attribute__((ext_vector_type(4)));

__device__ __forceinline__ unsigned short f2bf(float f) {
    unsigned u = __float_as_uint(f);
    u += 0x7FFFu + ((u >> 16) & 1u);        // RNE
    return (unsigned short)(u >> 16);
}
__device__ __forceinline__ float bf2f(unsigned short s) {
    return __uint_as_float(((unsigned)s) << 16);
}

// XOR swizzle of the 16B k-chunk within a 64B LDS row (kills ds_read_b128 bank conflicts)
#define SWZ(r) (((r) ^ ((r) >> 2)) & 3)

// async 16B global->LDS (DMA; LDS dest = wave-uniform base + lane*16)
__device__ __forceinline__ void async_ld16(const unsigned short* g, unsigned short* l) {
    __builtin_amdgcn_global_load_lds(
        (const __attribute__((address_space(1))) void*)g,
        (__attribute__((address_space(3))) void*)l,
        16, 0, 0);
}

#define LDH 40            // padded LDS row stride for prep_h0
#define ATS (256 * 32)    // one SA parity buffer: 256 rows x 32 shorts (16 KB)
#define BTS (64 * 32)     // one SB parity buffer: 64 rows x 32 shorts (4 KB)
#define AJ  136           // Achunk row stride: [i 64][j 128+8]
#define AGP 136           // l0 aggL row stride: [i 64][f 128+8]
#define AGP1 264          // l1 aggL row stride: [i 64][f 256+8]

// ============ FUSED layer 0: streamed gram + A@h + dense (A never global) ========
// Block = 64-node i-tile (8/graph, 512 blocks). Per j-tile (4 of 128): gram chunk
// S=exp(-dist/2s^2) -> Achunk LDS; then aggT += h0T[:,jchunk] @ Achunk. Then dense.
__global__ __launch_bounds__(512) void fused_l0(
    const unsigned short* __restrict__ h0T,   // [graph][128][512]
    const unsigned short* __restrict__ h0b,   // [node][128]
    const unsigned short* __restrict__ WrelT0,  // [256][128]
    const unsigned short* __restrict__ WrootT0, // [256][128]
    const float* __restrict__ sqv, const float* __restrict__ sigma,
    const float* __restrict__ brel0,
    unsigned short* __restrict__ h1b,  // [node][256]
    unsigned short* __restrict__ h1T)  // [graph][256][512]
{
    int id = blockIdx.x;
    int b = id & 63;               // graph (XCD locality)
    int nt = id >> 6;              // i-tile 0..7
    int n0g = nt * 64;
    long nodeBase = (long)b * Nn + n0g;

    const float* SQ = sqv + (long)b * Nn;

    __shared__ unsigned short SA[2 * ATS];   // 32 KB (gram stage / agg hT / dense W)
    __shared__ unsigned short SB[2 * BTS];   // 8 KB (dense h0b)
    __shared__ unsigned short AL[64 * AJ];   // 17.4 KB (Achunk, then aggL)

    int tid = threadIdx.x;
    int lane = tid & 63;
    int wave = tid >> 6;
    int quad = lane >> 4, l16 = lane & 15;
    int sr = lane >> 2, sc = lane & 3;

    float s = sigma[0];
    float inv2s2 = 1.0f / (2.0f * s * s);

    f32x4 agg[4] = {};   // aggT: M=128 feats (wave*16 rows), N=64 nodes

    for (int jt = 0; jt < 4; ++jt) {
        // --- gram: M = 128 j-nodes, N = 64 i-nodes, K = 128 feats ---
        auto issueG = [&](int ss) {
            unsigned short* d = SA + (ss & 1) * ATS;
            int r = wave * 16 + sr;
            int c = sc ^ SWZ(r);
            async_ld16(h0b + ((long)b * Nn + jt * 128 + r) * Ff + ss * 32 + c * 8,
                       d + (wave * 16) * 32);
            if (wave < 4)
                async_ld16(h0b + (nodeBase + r) * Ff + ss * 32 + c * 8,
                           d + (128 + wave * 16) * 32);
        };
        f32x4 gacc[4] = {};
        issueG(0);
        for (int ss = 0; ss < 4; ++ss) {
            __syncthreads();
            if (ss < 3) issueG(ss + 1);
            const unsigned short* Sg = SA + (ss & 1) * ATS;
            int jrow = wave * 16 + l16;
            bf16x8 af = *(const bf16x8*)&Sg[jrow * 32 + (quad ^ SWZ(jrow)) * 8];
            #pragma unroll
            for (int jj = 0; jj < 4; ++jj) {
                int irow = jj * 16 + l16;
                bf16x8 bf = *(const bf16x8*)&Sg[(128 + irow) * 32 + (quad ^ SWZ(irow)) * 8];
                gacc[jj] = __builtin_amdgcn_mfma_f32_16x16x32_bf16(af, bf, gacc[jj], 0, 0, 0);
            }
        }
        // epilogue: rows = j (quad*4+reg), cols = i(l16) -> packed Achunk[i][j]
        int jlb = wave * 16 + quad * 4;
        #pragma unroll
        for (int jj = 0; jj < 4; ++jj) {
            int il = jj * 16 + l16;
            int iG = n0g + il;
            float sqi = SQ[iG];
            f32x4 v = gacc[jj];
            ushort4v pk;
            #pragma unroll
            for (int r4 = 0; r4 < 4; ++r4) {
                int jG = jt * 128 + jlb + r4;
                float d = fmaxf(SQ[jG] + sqi - 2.0f * v[r4], 0.0f);
                pk[r4] = (jG == iG) ? (unsigned short)0 : f2bf(__expf(-d * inv2s2));
            }
            *(ushort4v*)&AL[il * AJ + jlb] = pk;
        }
        __syncthreads();   // Achunk visible; gram SA reads done

        // --- agg: aggT[f][i] += h0T[f][j-chunk] * Achunk, K = this j-tile (128) ---
        auto issueA = [&](int ss) {
            unsigned short* d = SA + (ss & 1) * ATS;
            int r = wave * 16 + sr;
            int c = sc ^ SWZ(r);
            async_ld16(h0T + ((long)b * Ff + r) * Nn + jt * 128 + ss * 32 + c * 8,
                       d + (wave * 16) * 32);
        };
        issueA(0);
        for (int ss = 0; ss < 4; ++ss) {
            __syncthreads();
            if (ss < 3) issueA(ss + 1);
            const unsigned short* Sg = SA + (ss & 1) * ATS;
            int frow = wave * 16 + l16;
            bf16x8 af = *(const bf16x8*)&Sg[frow * 32 + (quad ^ SWZ(frow)) * 8];
            #pragma unroll
            for (int jj = 0; jj < 4; ++jj) {
                int il = jj * 16 + l16;
                bf16x8 bf = *(const bf16x8*)&AL[il * AJ + ss * 32 + quad * 8];
                agg[jj] = __builtin_amdgcn_mfma_f32_16x16x32_bf16(af, bf, agg[jj], 0, 0, 0);
            }
        }
        __syncthreads();   // AL reads done (next jt overwrites), SA free
    }

    // write aggL[i][f] (f2bf, packed); overwrites Achunk region
    {
        int fb = wave * 16 + quad * 4;
        #pragma unroll
        for (int jj = 0; jj < 4; ++jj) {
            int il = jj * 16 + l16;
            f32x4 v = agg[jj];
            ushort4v p;
            p[0] = f2bf(v[0]); p[1] = f2bf(v[1]); p[2] = f2bf(v[2]); p[3] = f2bf(v[3]);
            *(ushort4v*)&AL[il * AGP + fb] = p;
        }
    }
    __syncthreads();

    // --- dense: h1^T = Wrel0^T@agg^T + Wroot0^T@h0^T + bias, relu ---
    f32x4 acc2[2][4] = {};
    auto issue2 = [&](int g) {
        const unsigned short* Wp = (g < 4) ? WrelT0 : WrootT0;
        int kk = (g & 3) << 5;
        unsigned short* d = SA + (g & 1) * ATS;
        int r = wave * 16 + sr;
        int c = sc ^ SWZ(r);
        async_ld16(Wp + (long)r * Ff + kk + c * 8, d + (wave * 16) * 32);
        int r2 = 128 + r;
        int c2 = sc ^ SWZ(r2);
        async_ld16(Wp + (long)r2 * Ff + kk + c2 * 8, d + (128 + wave * 16) * 32);
        if (g >= 4 && wave < 4)
            async_ld16(h0b + (nodeBase + r) * Ff + kk + c * 8,
                       SB + (g & 1) * BTS + (wave * 16) * 32);
    };
    issue2(0);
    for (int g = 0; g < 8; ++g) {
        __syncthreads();
        if (g < 7) issue2(g + 1);
        const unsigned short* Sg = SA + (g & 1) * ATS;
        bf16x8 af[2], bfr[4];
        #pragma unroll
        for (int i = 0; i < 2; ++i) {
            int row = wave * 32 + i * 16 + l16;
            af[i] = *(const bf16x8*)&Sg[row * 32 + (quad ^ SWZ(row)) * 8];
        }
        if (g < 4) {
            #pragma unroll
            for (int jj = 0; jj < 4; ++jj) {
                int il = jj * 16 + l16;
                bfr[jj] = *(const bf16x8*)&AL[il * AGP + (g << 5) + quad * 8];
            }
        } else {
            const unsigned short* Bb = SB + (g & 1) * BTS;
            #pragma unroll
            for (int jj = 0; jj < 4; ++jj) {
                int irow = jj * 16 + l16;
                bfr[jj] = *(const bf16x8*)&Bb[irow * 32 + (quad ^ SWZ(irow)) * 8];
            }
        }
        #pragma unroll
        for (int i = 0; i < 2; ++i)
            #pragma unroll
            for (int jj = 0; jj < 4; ++jj)
                acc2[i][jj] = __builtin_amdgcn_mfma_f32_16x16x32_bf16(
                    af[i], bfr[jj], acc2[i][jj], 0, 0, 0);
    }
    #pragma unroll
    for (int i = 0; i < 2; ++i) {
        int of = wave * 32 + i * 16 + quad * 4;
        float b0 = brel0[of + 0], b1 = brel0[of + 1];
        float b2 = brel0[of + 2], b3 = brel0[of + 3];
        #pragma unroll
        for (int jj = 0; jj < 4; ++jj) {
            int nl = jj * 16 + l16;
            f32x4 v = acc2[i][jj];
            float o0 = fmaxf(v[0] + b0, 0.f), o1 = fmaxf(v[1] + b1, 0.f);
            float o2 = fmaxf(v[2] + b2, 0.f), o3 = fmaxf(v[3] + b3, 0.f);
            ushort4v p;
            p[0] = f2bf(o0); p[1] = f2bf(o1); p[2] = f2bf(o2); p[3] = f2bf(o3);
            *(ushort4v*)&h1b[(nodeBase + nl) * Hh + of] = p;
            long base = ((long)b * Hh) * 512 + n0g + nl;
            h1T[base + (long)(of + 0) * 512] = p[0];
            h1T[base + (long)(of + 1) * 512] = p[1];
            h1T[base + (long)(of + 2) * 512] = p[2];
            h1T[base + (long)(of + 3) * 512] = p[3];
        }
    }
}

// ============ FUSED layer 1: streamed gram + A@h + dense + pooled collapse =======
// Same skeleton; agg M=256 (h1T), dense K=256+256, w accumulated locally, h2 never
// stored — pooled partials out.
__global__ __launch_bounds__(512) void fused_l1(
    const unsigned short* __restrict__ h1T,   // [graph][256][512]
    const unsigned short* __restrict__ h0b,   // [node][128] (gram source)
    const unsigned short* __restrict__ h1b,   // [node][256]
    const unsigned short* __restrict__ WrelT1,  // [256][256]
    const unsigned short* __restrict__ WrootT1, // [256][256]
    const float* __restrict__ sqv, const float* __restrict__ sigma,
    const float* __restrict__ brel1,
    float* __restrict__ vpart, float* __restrict__ mpart)  // [512][256]
{
    int id = blockIdx.x;
    int b = id & 63;
    int nt = id >> 6;              // i-tile 0..7
    int n0g = nt * 64;
    long nodeBase = (long)b * Nn + n0g;

    const float* SQ = sqv + (long)b * Nn;

    __shared__ unsigned short SA[2 * ATS];     // 32 KB
    __shared__ unsigned short SB[2 * BTS];     // 8 KB
    __shared__ unsigned short AL[64 * AGP1];   // 33.8 KB (Achunk then aggL)
    __shared__ float wloc[64];

    int tid = threadIdx.x;
    int lane = tid & 63;
    int wave = tid >> 6;
    int quad = lane >> 4, l16 = lane & 15;
    int sr = lane >> 2, sc = lane & 3;

    if (tid < 64) wloc[tid] = 0.f;

    float s = sigma[0];
    float inv2s2 = 1.0f / (2.0f * s * s);

    f32x4 agg[2][4] = {};   // aggT: M=256 feats (wave*32 rows), N=64 nodes

    for (int jt = 0; jt < 4; ++jt) {
        // --- gram (h0b): M = 128 j, N = 64 i, K = 128 ---
        auto issueG = [&](int ss) {
            unsigned short* d = SA + (ss & 1) * ATS;
            int r = wave * 16 + sr;
            int c = sc ^ SWZ(r);
            async_ld16(h0b + ((long)b * Nn + jt * 128 + r) * Ff + ss * 32 + c * 8,
                       d + (wave * 16) * 32);
            if (wave < 4)
                async_ld16(h0b + (nodeBase + r) * Ff + ss * 32 + c * 8,
                           d + (128 + wave * 16) * 32);
        };
        f32x4 gacc[4] = {};
        issueG(0);
        for (int ss = 0; ss < 4; ++ss) {
            __syncthreads();
            if (ss < 3) issueG(ss + 1);
            const unsigned short* Sg = SA + (ss & 1) * ATS;
            int jrow = wave * 16 + l16;
            bf16x8 af = *(const bf16x8*)&Sg[jrow * 32 + (quad ^ SWZ(jrow)) * 8];
            #pragma unroll
            for (int jj = 0; jj < 4; ++jj) {
                int irow = jj * 16 + l16;
                bf16x8 bf = *(const bf16x8*)&Sg[(128 + irow) * 32 + (quad ^ SWZ(irow)) * 8];
                gacc[jj] = __builtin_amdgcn_mfma_f32_16x16x32_bf16(af, bf, gacc[jj], 0, 0, 0);
            }
        }
        int jlb = wave * 16 + quad * 4;
        #pragma unroll
        for (int jj = 0; jj < 4; ++jj) {
            int il = jj * 16 + l16;
            int iG = n0g + il;
            float sqi = SQ[iG];
            f32x4 v = gacc[jj];
            ushort4v pk;
            float cw = 0.f;
            #pragma unroll
            for (int r4 = 0; r4 < 4; ++r4) {
                int jG = jt * 128 + jlb + r4;
                float d = fmaxf(SQ[jG] + sqi - 2.0f * v[r4], 0.0f);
                unsigned short a = (jG == iG) ? (unsigned short)0
                                              : f2bf(__expf(-d * inv2s2));
                pk[r4] = a;
                cw += bf2f(a);
            }
            *(ushort4v*)&AL[il * AJ + jlb] = pk;
            // w[i] partial: reduce over quads (lanes sharing il within wave)
            cw += __shfl_xor(cw, 16);
            cw += __shfl_xor(cw, 32);
            if (quad == 0) atomicAdd(&wloc[il], cw);
        }
        __syncthreads();

        // --- agg (h1T): M = 256 feats, K = this j-tile ---
        auto issueA = [&](int ss) {
            unsigned short* d = SA + (ss & 1) * ATS;
            int r = wave * 16 + sr;
            int c = sc ^ SWZ(r);
            async_ld16(h1T + ((long)b * Hh + r) * Nn + jt * 128 + ss * 32 + c * 8,
                       d + (wave * 16) * 32);
            int r2 = 128 + r;
            int c2 = sc ^ SWZ(r2);
            async_ld16(h1T + ((long)b * Hh + r2) * Nn + jt * 128 + ss * 32 + c2 * 8,
                       d + (128 + wave * 16) * 32);
        };
        issueA(0);
        for (int ss = 0; ss < 4; ++ss) {
            __syncthreads();
            if (ss < 3) issueA(ss + 1);
            const unsigned short* Sg = SA + (ss & 1) * ATS;
            bf16x8 af[2];
            #pragma unroll
            for (int i = 0; i < 2; ++i) {
                int frow = wave * 32 + i * 16 + l16;
                af[i] = *(const bf16x8*)&Sg[frow * 32 + (quad ^ SWZ(frow)) * 8];
            }
            #pragma unroll
            for (int jj = 0; jj < 4; ++jj) {
                int il = jj * 16 + l16;
                bf16x8 bf = *(const bf16x8*)&AL[il * AJ + ss * 32 + quad * 8];
                #pragma unroll
                for (int i = 0; i < 2; ++i)
                    agg[i][jj] = __builtin_amdgcn_mfma_f32_16x16x32_bf16(
                        af[i], bf, agg[i][jj], 0, 0, 0);
            }
        }
        __syncthreads();
    }

    // write aggL[i][f 256] (overwrites Achunk region)
    #pragma unroll
    for (int i = 0; i < 2; ++i) {
        int fb = wave * 32 + i * 16 + quad * 4;
        #pragma unroll
        for (int jj = 0; jj < 4; ++jj) {
            int il = jj * 16 + l16;
            f32x4 v = agg[i][jj];
            ushort4v p;
            p[0] = f2bf(v[0]); p[1] = f2bf(v[1]); p[2] = f2bf(v[2]); p[3] = f2bf(v[3]);
            *(ushort4v*)&AL[il * AGP1 + fb] = p;
        }
    }
    __syncthreads();

    // --- dense: h2^T = Wrel1^T@agg^T + Wroot1^T@h1^T + bias, relu; pooled ---
    f32x4 acc2[2][4] = {};
    auto issue2 = [&](int g) {
        const unsigned short* Wp = (g < 8) ? WrelT1 : WrootT1;
        int kk = (g & 7) << 5;
        unsigned short* d = SA + (g & 1) * ATS;
        int r = wave * 16 + sr;
        int c = sc ^ SWZ(r);
        async_ld16(Wp + (long)r * Hh + kk + c * 8, d + (wave * 16) * 32);
        int r2 = 128 + r;
        int c2 = sc ^ SWZ(r2);
        async_ld16(Wp + (long)r2 * Hh + kk + c2 * 8, d + (128 + wave * 16) * 32);
        if (g >= 8 && wave < 4)
            async_ld16(h1b + (nodeBase + r) * Hh + kk + c * 8,
                       SB + (g & 1) * BTS + (wave * 16) * 32);
    };
    issue2(0);
    for (int g = 0; g < 16; ++g) {
        __syncthreads();
        if (g < 15) issue2(g + 1);
        const unsigned short* Sg = SA + (g & 1) * ATS;
        bf16x8 af[2], bfr[4];
        #pragma unroll
        for (int i = 0; i < 2; ++i) {
            int row = wave * 32 + i * 16 + l16;
            af[i] = *(const bf16x8*)&Sg[row * 32 + (quad ^ SWZ(row)) * 8];
        }
        if (g < 8) {
            #pragma unroll
            for (int jj = 0; jj < 4; ++jj) {
                int il = jj * 16 + l16;
                bfr[jj] = *(const bf16x8*)&AL[il * AGP1 + (g << 5) + quad * 8];
            }
        } else {
            const unsigned short* Bb = SB + (g & 1) * BTS;
            #pragma unroll
            for (int jj = 0; jj < 4; ++jj) {
                int irow = jj * 16 + l16;
                bfr[jj] = *(const bf16x8*)&Bb[irow * 32 + (quad ^ SWZ(irow)) * 8];
            }
        }
        #pragma unroll
        for (int i = 0; i < 2; ++i)
            #pragma unroll
            for (int jj = 0; jj < 4; ++jj)
                acc2[i][jj] = __builtin_amdgcn_mfma_f32_16x16x32_bf16(
                    af[i], bfr[jj], acc2[i][jj], 0, 0, 0);
    }

    // pooled epilogue: unique feats per (wave,quad,i); w from wloc
    #pragma unroll
    for (int i = 0; i < 2; ++i) {
        int lf = wave * 32 + i * 16 + quad * 4;
        float b0 = brel1[lf + 0], b1 = brel1[lf + 1];
        float b2 = brel1[lf + 2], b3 = brel1[lf + 3];
        float vp0 = 0.f, vp1 = 0.f, vp2 = 0.f, vp3 = 0.f;
        float mp0 = 0.f, mp1 = 0.f, mp2 = 0.f, mp3 = 0.f;
        #pragma unroll
        for (int jj = 0; jj < 4; ++jj) {
            int nl = jj * 16 + l16;
            f32x4 v = acc2[i][jj];
            float o0 = fmaxf(v[0] + b0, 0.f), o1 = fmaxf(v[1] + b1, 0.f);
            float o2 = fmaxf(v[2] + b2, 0.f), o3 = fmaxf(v[3] + b3, 0.f);
            float h0v = bf2f(f2bf(o0)), h1v = bf2f(f2bf(o1));
            float h2v = bf2f(f2bf(o2)), h3v = bf2f(f2bf(o3));
            float wv = wloc[nl];
            vp0 += wv * h0v; vp1 += wv * h1v; vp2 += wv * h2v; vp3 += wv * h3v;
            mp0 += h0v; mp1 += h1v; mp2 += h2v; mp3 += h3v;
        }
        #pragma unroll
        for (int m = 1; m < 16; m <<= 1) {
            vp0 += __shfl_xor(vp0, m); vp1 += __shfl_xor(vp1, m);
            vp2 += __shfl_xor(vp2, m); vp3 += __shfl_xor(vp3, m);
            mp0 += __shfl_xor(mp0, m); mp1 += __shfl_xor(mp1, m);
            mp2 += __shfl_xor(mp2, m); mp3 += __shfl_xor(mp3, m);
        }
        if (l16 == 0) {
            long o = ((long)(b * 8 + nt)) * Hh + lf;
            float4 vv = {vp0, vp1, vp2, vp3};
            float4 mm = {mp0, mp1, mp2, mp3};
            *(float4*)&vpart[o] = vv;
            *(float4*)&mpart[o] = mm;
        }
    }
}

// ---------------- prep: weight convert/transpose + h0 MFMA ------------
// blocks [0, 768): convert; blocks [768, 1024): h0 (m0 = (blk-768)*128)
__global__ __launch_bounds__(256) void prep_h0(
    const float* __restrict__ x, const float* __restrict__ Wg,
    const float* __restrict__ bg,
    const float* __restrict__ Wrel0, const float* __restrict__ Wroot0,
    const float* __restrict__ Wrel1, const float* __restrict__ Wroot1,
    unsigned short* __restrict__ T0, unsigned short* __restrict__ T1,
    unsigned short* __restrict__ T2, unsigned short* __restrict__ T3,
    unsigned short* __restrict__ h0b, unsigned short* __restrict__ h0T,
    float* __restrict__ sqv)
{
    if (blockIdx.x < 768) {
        int idx = blockIdx.x * 256 + threadIdx.x;    // 0..196607
        const float* src; unsigned short* dst; int kin; int e;
        if      (idx <  32768) { src = Wrel0;  dst = T0; kin = 128; e = idx; }
        else if (idx <  65536) { src = Wroot0; dst = T1; kin = 128; e = idx - 32768; }
        else if (idx < 131072) { src = Wrel1;  dst = T2; kin = 256; e = idx - 65536; }
        else                   { src = Wroot1; dst = T3; kin = 256; e = idx - 131072; }
        int o = (kin == 128) ? (e >> 7) : (e >> 8);
        int i = e & (kin - 1);
        dst[e] = f2bf(src[(long)i * 256 + o]);       // conv out-dims are all 256
        return;
    }

    // ---- h0 branch: converts Wg on the fly ----
    __shared__ unsigned short As[128 * LDH];
    __shared__ unsigned short Bs[128 * LDH];
    __shared__ float rsq[128];

    int tid = threadIdx.x;
    int lane = tid & 63;
    int wave = tid >> 6;
    int quad = lane >> 4, l16 = lane & 15;
    int wm = (wave >> 1) * 64, wn = (wave & 1) * 64;
    int m0 = (blockIdx.x - 768) * 128;

    f32x4 acc[4][4] = {};

    for (int k0 = 0; k0 < Ff; k0 += 32) {
        __syncthreads();
        #pragma unroll
        for (int l = 0; l < 2; ++l) {
            int idx = tid + l * 256;
            int r = idx >> 2, ch = idx & 3;
            const float* px = x + (long)(m0 + r) * Ff + k0 + ch * 8;
            float4 xa = *(const float4*)px;
            float4 xb = *(const float4*)(px + 4);
            ushort4v pa, pb;
            pa[0] = f2bf(xa.x); pa[1] = f2bf(xa.y); pa[2] = f2bf(xa.z); pa[3] = f2bf(xa.w);
            pb[0] = f2bf(xb.x); pb[1] = f2bf(xb.y); pb[2] = f2bf(xb.z); pb[3] = f2bf(xb.w);
            *(ushort4v*)&As[r * LDH + ch * 8] = pa;
            *(ushort4v*)&As[r * LDH + ch * 8 + 4] = pb;
            int kk = k0 + ch * 8;
            ushort4v qa, qb;
            #pragma unroll
            for (int u = 0; u < 4; ++u) qa[u] = f2bf(Wg[(long)(kk + u) * 128 + r]);
            #pragma unroll
            for (int u = 0; u < 4; ++u) qb[u] = f2bf(Wg[(long)(kk + 4 + u) * 128 + r]);
            *(ushort4v*)&Bs[r * LDH + ch * 8] = qa;
            *(ushort4v*)&Bs[r * LDH + ch * 8 + 4] = qb;
        }
        __syncthreads();
        bf16x8 af[4], bfr[4];
        #pragma unroll
        for (int i = 0; i < 4; ++i)
            af[i] = *(const bf16x8*)&As[(wm + i * 16 + l16) * LDH + quad * 8];
        #pragma unroll
        for (int j = 0; j < 4; ++j)
            bfr[j] = *(const bf16x8*)&Bs[(wn + j * 16 + l16) * LDH + quad * 8];
        #pragma unroll
        for (int i = 0; i < 4; ++i)
            #pragma unroll
            for (int j = 0; j < 4; ++j)
                acc[i][j] = __builtin_amdgcn_mfma_f32_16x16x32_bf16(
                    af[i], bfr[j], acc[i][j], 0, 0, 0);
    }

    if (tid < 128) rsq[tid] = 0.f;
    __syncthreads();

    #pragma unroll
    for (int i = 0; i < 4; ++i) {
        int lrow = wm + i * 16 + quad * 4;
        int mb = m0 + lrow;
        float rp0 = 0.f, rp1 = 0.f, rp2 = 0.f, rp3 = 0.f;
        #pragma unroll
        for (int j = 0; j < 4; ++j) {
            int n = wn + j * 16 + l16;
            f32x4 v = acc[i][j];
            float bv = bg[n];
            unsigned short s0 = f2bf(v[0] + bv), s1 = f2bf(v[1] + bv);
            unsigned short s2 = f2bf(v[2] + bv), s3 = f2bf(v[3] + bv);
            h0b[(long)(mb + 0) * Ff + n] = s0;
            h0b[(long)(mb + 1) * Ff + n] = s1;
            h0b[(long)(mb + 2) * Ff + n] = s2;
            h0b[(long)(mb + 3) * Ff + n] = s3;
            ushort4v p; p[0] = s0; p[1] = s1; p[2] = s2; p[3] = s3;
            long ti = ((long)(mb >> 9) * Ff + n) * 512 + (mb & 511);
            *(ushort4v*)&h0T[ti] = p;
            float f0 = bf2f(s0), f1 = bf2f(s1), f2 = bf2f(s2), f3 = bf2f(s3);
            rp0 += f0 * f0; rp1 += f1 * f1; rp2 += f2 * f2; rp3 += f3 * f3;
        }
        #pragma unroll
        for (int m = 1; m < 16; m <<= 1) {
            rp0 += __shfl_xor(rp0, m);
            rp1 += __shfl_xor(rp1, m);
            rp2 += __shfl_xor(rp2, m);
            rp3 += __shfl_xor(rp3, m);
        }
        if (l16 == 0) {
            atomicAdd(&rsq[lrow + 0], rp0);
            atomicAdd(&rsq[lrow + 1], rp1);
            atomicAdd(&rsq[lrow + 2], rp2);
            atomicAdd(&rsq[lrow + 3], rp3);
        }
    }
    __syncthreads();
    if (tid < 128) sqv[m0 + tid] = rsq[tid];
}

// ---------------- head: sum 8 nodeblock partials + layer2-collapse + mean + MLP ----
__global__ __launch_bounds__(256) void head_kernel(
    const float* __restrict__ vpart, const float* __restrict__ mpart,
    const float* __restrict__ Wrel2, const float* __restrict__ Wroot2,
    const float* __restrict__ brel2,
    const float* __restrict__ W1, const float* __restrict__ b1,
    const float* __restrict__ Wout, const float* __restrict__ bout,
    float* __restrict__ out)
{
    int b = blockIdx.x;
    int j = threadIdx.x;
    __shared__ float vs[Hh], ms[Hh], gs[Hh], g2[Hh];
    float vp = 0.f, mp = 0.f;
    #pragma unroll
    for (int p = 0; p < 8; ++p) {
        long o = ((long)(b * 8 + p)) * Hh + j;
        vp += vpart[o];
        mp += mpart[o];
    }
    vs[j] = vp * (1.0f / (float)Nn);
    ms[j] = mp * (1.0f / (float)Nn);
    __syncthreads();
    float s = brel2[j];
    for (int c = 0; c < Hh; ++c)
        s += vs[c] * Wrel2[c * Hh + j] + ms[c] * Wroot2[c * Hh + j];
    gs[j] = s;
    __syncthreads();
    float t = b1[j];
    for (int k = 0; k < Hh; ++k) t += gs[k] * W1[k * Hh + j];
    g2[j] = fmaxf(t, 0.f);
    __syncthreads();
    if (j < OUTD) {
        float s2 = bout[j];
        for (int k = 0; k < Hh; ++k) s2 += g2[k] * Wout[k * OUTD + j];
        out[b * OUTD + j] = s2;
    }
}

extern "C" void kernel_launch(void* const* d_in, const int* in_sizes, int n_in,
                              void* d_out, int out_size, void* d_ws, size_t ws_size,
                              hipStream_t stream) {
    const float* x      = (const float*)d_in[0];
    const float* sigma  = (const float*)d_in[4];
    const float* Wg     = (const float*)d_in[5];
    const float* bg     = (const float*)d_in[6];
    const float* Wrel0  = (const float*)d_in[7];
    const float* Wroot0 = (const float*)d_in[8];
    const float* brel0  = (const float*)d_in[9];
    const float* Wrel1  = (const float*)d_in[10];
    const float* Wroot1 = (const float*)d_in[11];
    const float* brel1  = (const float*)d_in[12];
    const float* Wrel2  = (const float*)d_in[13];
    const float* Wroot2 = (const float*)d_in[14];
    const float* brel2  = (const float*)d_in[15];
    const float* W1     = (const float*)d_in[16];
    const float* b1     = (const float*)d_in[17];
    const float* Wout   = (const float*)d_in[18];
    const float* bout   = (const float*)d_in[19];
    float* out = (float*)d_out;

    // Workspace layout (bytes)
    char* ws = (char*)d_ws;
    unsigned short* h0b  = (unsigned short*)(ws + 16777216);       // 8 MB
    unsigned short* h0T  = (unsigned short*)(ws + 25165824);       // 8 MB
    float*          sq   = (float*)(ws + 33554432);                // 128 KB
    unsigned short* h1b  = (unsigned short*)(ws + 84017152);       // 16 MB
    unsigned short* h1T  = (unsigned short*)(ws + 100794368);      // 16 MB
    unsigned short* WrelT0  = (unsigned short*)(ws + 167903232);   // 64 KB
    unsigned short* WrootT0 = (unsigned short*)(ws + 167968768);   // 64 KB
    unsigned short* WrelT1  = (unsigned short*)(ws + 168034304);   // 128 KB
    unsigned short* WrootT1 = (unsigned short*)(ws + 168165376);   // 128 KB
    float*          vpart = (float*)(ws + 168689664);              // 512 KB
    float*          mpart = (float*)(ws + 169213952);              // 512 KB

    // prep (weights) and h0 in one dispatch
    prep_h0<<<1024, 256, 0, stream>>>(x, Wg, bg, Wrel0, Wroot0, Wrel1, Wroot1,
                                      WrelT0, WrootT0, WrelT1, WrootT1,
                                      h0b, h0T, sq);

    // layer 0: streamed gram + A@h + dense (A never materialized)
    fused_l0<<<dim3(8 * Bsz, 1, 1), 512, 0, stream>>>(
        h0T, h0b, WrelT0, WrootT0, sq, sigma, brel0, h1b, h1T);

    // layer 1: streamed gram + A@h + dense + layer-2-collapse pooling
    fused_l1<<<dim3(8 * Bsz, 1, 1), 512, 0, stream>>>(
        h1T, h0b, h1b, WrelT1, WrootT1, sq, sigma, brel1, vpart, mpart);

    // head (sum partials + layer-2 projection + mean + 2-layer MLP)
    head_kernel<<<Bsz, 256, 0, stream>>>(vpart, mpart, Wrel2, Wroot2, brel2,
                                         W1, b1, Wout, bout, out);
}

// Round 19
// 212.745 us; speedup vs baseline: 1.0508x; 1.0508x over previous
//
#include <hip/hip_runtime.h>
#include <math.h>

// Problem constants
#define Bsz 64
#define Nn 512
#define Ff 128
#define Hh 256
#define OUTD 6
#define MTOT (Bsz * Nn)   // 32768

typedef __bf16 bf16x8 __attribute__((ext_vector_type(8)));
typedef float f32x4 __attribute__((ext_vector_type(4)));
typedef int int4v __attribute__((ext_vector_type(4)));
typedef unsigned short ushort4v __attribute__((ext_vector_type(4)));

__device__ __forceinline__ unsigned short f2bf(float f) {
    unsigned u = __float_as_uint(f);
    u += 0x7FFFu + ((u >> 16) & 1u);        // RNE
    return (unsigned short)(u >> 16);
}
__device__ __forceinline__ float bf2f(unsigned short s) {
    return __uint_as_float(((unsigned)s) << 16);
}

// XOR swizzle of the 16B k-chunk within a 64B LDS row (kills ds_read_b128 bank conflicts)
#define SWZ(r) (((r) ^ ((r) >> 2)) & 3)

// async 16B global->LDS (DMA; LDS dest = wave-uniform base + lane*16)
__device__ __forceinline__ void async_ld16(const unsigned short* g, unsigned short* l) {
    __builtin_amdgcn_global_load_lds(
        (const __attribute__((address_space(1))) void*)g,
        (__attribute__((address_space(3))) void*)l,
        16, 0, 0);
}

#define LDH 40           // padded LDS row stride (bf16) for the non-async h0 kernel
#define TSZ (128 * 32)   // one LDS tile: 128 rows x 32 bf16 (8 KB)
#define AGP 136          // fused_l0 aggL row stride (128 + 8 pad)
#define AGP1 264         // fused_l1 aggL row stride (256 + 8 pad; 16B-aligned, 2-way alias)

// ---------------- FUSED layer 0: A@h (K=512) + dense (K=128+128) -----------------
// One block per 128-node tile. Stage 1 = A@h0 tile into LDS (bf16-rounded). Stage 2 =
// dense in two 128-outfeat halves; agg K-half reads fragments straight from LDS.
__global__ __launch_bounds__(512) void fused_l0(
    const unsigned short* __restrict__ h0T,   // [graph][128][512]
    const unsigned short* __restrict__ Arows, // [graph][512][512]
    const unsigned short* __restrict__ h0b,   // [node][128]
    const unsigned short* __restrict__ WrelT0,  // [256][128]
    const unsigned short* __restrict__ WrootT0, // [256][128]
    const float* __restrict__ brel0,
    unsigned short* __restrict__ h1b,  // [node][256]
    unsigned short* __restrict__ h1T)  // [graph][256][512]
{
    int id = blockIdx.x;
    int b = id & 63;               // graph (XCD locality)
    int nt = id >> 6;              // node tile 0..3
    int n0g = nt * 128;
    long nodeBase = (long)b * Nn + n0g;

    const unsigned short* HT = h0T + (long)b * Ff * Nn;
    const unsigned short* AR = Arows + (long)b * Nn * Nn;

    __shared__ unsigned short SA[2 * TSZ];
    __shared__ unsigned short SB[2 * TSZ];
    __shared__ unsigned short aggL[128 * AGP];

    int tid = threadIdx.x;
    int lane = tid & 63;
    int wave = tid >> 6;
    int quad = lane >> 4, l16 = lane & 15;
    int wm = (wave >> 1) * 32, wn = (wave & 1) * 64;
    int sr = lane >> 2, sc = lane & 3;

    // ---------- stage 1: agg tile = A@h0 (M=128 feats, N=128 nodes, K=512) ----------
    {
        f32x4 acc[2][4] = {};
        auto issue = [&](int g) {
            int kk = g << 5;
            unsigned short* Ad = SA + (g & 1) * TSZ;
            unsigned short* Bd = SB + (g & 1) * TSZ;
            int r = wave * 16 + sr;
            int c = sc ^ SWZ(r);
            async_ld16(HT + (long)r * Nn + kk + c * 8, Ad + (wave * 16) * 32);
            async_ld16(AR + (long)(n0g + r) * Nn + kk + c * 8, Bd + (wave * 16) * 32);
        };
        issue(0);
        for (int g = 0; g < (Nn >> 5); ++g) {
            __syncthreads();
            if (g + 1 < (Nn >> 5)) issue(g + 1);
            const unsigned short* Ab = SA + (g & 1) * TSZ;
            const unsigned short* Bb = SB + (g & 1) * TSZ;
            bf16x8 af[2], bfr[4];
            #pragma unroll
            for (int i = 0; i < 2; ++i) {
                int r = wm + i * 16 + l16;
                af[i] = *(const bf16x8*)&Ab[r * 32 + (quad ^ SWZ(r)) * 8];
            }
            #pragma unroll
            for (int j = 0; j < 4; ++j) {
                int r = wn + j * 16 + l16;
                bfr[j] = *(const bf16x8*)&Bb[r * 32 + (quad ^ SWZ(r)) * 8];
            }
            #pragma unroll
            for (int i = 0; i < 2; ++i)
                #pragma unroll
                for (int j = 0; j < 4; ++j)
                    acc[i][j] = __builtin_amdgcn_mfma_f32_16x16x32_bf16(
                        af[i], bfr[j], acc[i][j], 0, 0, 0);
        }
        // epilogue 1: bf16-round into aggL[node][feat] (packed 8B, 2-way alias only)
        #pragma unroll
        for (int i = 0; i < 2; ++i) {
            int f = wm + i * 16 + quad * 4;
            #pragma unroll
            for (int j = 0; j < 4; ++j) {
                int nl = wn + j * 16 + l16;
                f32x4 v = acc[i][j];
                ushort4v p;
                p[0] = f2bf(v[0]); p[1] = f2bf(v[1]);
                p[2] = f2bf(v[2]); p[3] = f2bf(v[3]);
                *(ushort4v*)&aggL[nl * AGP + f] = p;
            }
        }
    }
    __syncthreads();   // aggL complete; stage-1 LDS reads all drained

    // ---------- stage 2: dense, two 128-outfeat halves ----------
    for (int half = 0; half < 2; ++half) {
        int m0 = half * 128;
        f32x4 acc[2][4] = {};
        // k-tiles: g in [0,4) -> Wrel x aggL (B from LDS); g in [4,8) -> Wroot x h0b
        auto issue = [&](int g) {
            unsigned short* Ad = SA + (g & 1) * TSZ;
            int r = wave * 16 + sr;
            int c = sc ^ SWZ(r);
            if (g < 4) {
                async_ld16(WrelT0 + (long)(m0 + r) * Ff + (g << 5) + c * 8,
                           Ad + (wave * 16) * 32);
            } else {
                async_ld16(WrootT0 + (long)(m0 + r) * Ff + ((g - 4) << 5) + c * 8,
                           Ad + (wave * 16) * 32);
                unsigned short* Bd = SB + (g & 1) * TSZ;
                async_ld16(h0b + (nodeBase + r) * Ff + ((g - 4) << 5) + c * 8,
                           Bd + (wave * 16) * 32);
            }
        };
        issue(0);
        for (int g = 0; g < 8; ++g) {
            __syncthreads();
            if (g + 1 < 8) issue(g + 1);
            const unsigned short* Ab = SA + (g & 1) * TSZ;
            bf16x8 af[2], bfr[4];
            #pragma unroll
            for (int i = 0; i < 2; ++i) {
                int r = wm + i * 16 + l16;
                af[i] = *(const bf16x8*)&Ab[r * 32 + (quad ^ SWZ(r)) * 8];
            }
            if (g < 4) {
                #pragma unroll
                for (int j = 0; j < 4; ++j) {
                    int nl = wn + j * 16 + l16;
                    bfr[j] = *(const bf16x8*)&aggL[nl * AGP + (g << 5) + quad * 8];
                }
            } else {
                const unsigned short* Bb = SB + (g & 1) * TSZ;
                #pragma unroll
                for (int j = 0; j < 4; ++j) {
                    int r = wn + j * 16 + l16;
                    bfr[j] = *(const bf16x8*)&Bb[r * 32 + (quad ^ SWZ(r)) * 8];
                }
            }
            #pragma unroll
            for (int i = 0; i < 2; ++i)
                #pragma unroll
                for (int j = 0; j < 4; ++j)
                    acc[i][j] = __builtin_amdgcn_mfma_f32_16x16x32_bf16(
                        af[i], bfr[j], acc[i][j], 0, 0, 0);
        }
        #pragma unroll
        for (int i = 0; i < 2; ++i) {
            int of = m0 + wm + i * 16 + quad * 4;
            float b0 = brel0[of + 0], b1 = brel0[of + 1];
            float b2 = brel0[of + 2], b3 = brel0[of + 3];
            #pragma unroll
            for (int j = 0; j < 4; ++j) {
                int nl = wn + j * 16 + l16;
                f32x4 v = acc[i][j];
                float o0 = fmaxf(v[0] + b0, 0.f), o1 = fmaxf(v[1] + b1, 0.f);
                float o2 = fmaxf(v[2] + b2, 0.f), o3 = fmaxf(v[3] + b3, 0.f);
                ushort4v p;
                p[0] = f2bf(o0); p[1] = f2bf(o1); p[2] = f2bf(o2); p[3] = f2bf(o3);
                *(ushort4v*)&h1b[(nodeBase + nl) * Hh + of] = p;
                long base = ((long)b * Hh) * 512 + n0g + nl;
                h1T[base + (long)(of + 0) * 512] = p[0];
                h1T[base + (long)(of + 1) * 512] = p[1];
                h1T[base + (long)(of + 2) * 512] = p[2];
                h1T[base + (long)(of + 3) * 512] = p[3];
            }
        }
    }
}

// ---------------- FUSED layer 1 + layer-2-collapse pooling -----------------------
// One block per 64-node tile (8/graph, 512 blocks). Stage 1: aggT = h1T@A
// (M=256 feats, N=64 nodes, K=512; wave tile 32x64, 64 MFMA/barrier) -> aggL in LDS.
// Stage 2: h2^T = Wrel1^T@agg^T + Wroot1^T@h1^T + bias, relu — never stored;
// pooled epilogue writes w-weighted + plain column-sum partials (direct stores).
__global__ __launch_bounds__(512) void fused_l1(
    const unsigned short* __restrict__ h1T,   // [graph][256][512]
    const unsigned short* __restrict__ Arows, // [graph][512][512]
    const unsigned short* __restrict__ h1b,   // [node][256]
    const unsigned short* __restrict__ WrelT1,  // [256][256]
    const unsigned short* __restrict__ WrootT1, // [256][256]
    const float* __restrict__ brel1,
    const float* __restrict__ w,
    float* __restrict__ vpart, float* __restrict__ mpart)  // [512][256]
{
    constexpr int ATS = 256 * 32;   // A-op tile shorts (16 KB)
    constexpr int BTS = 64 * 32;    // B-op tile shorts (4 KB)

    int id = blockIdx.x;
    int b = id & 63;               // graph (XCD locality)
    int nt = id >> 6;              // node tile 0..7
    int n0g = nt * 64;
    long nodeBase = (long)b * Nn + n0g;

    const unsigned short* HT = h1T + (long)b * Hh * Nn;
    const unsigned short* AR = Arows + (long)b * Nn * Nn;

    __shared__ unsigned short SA[2 * ATS];     // 32 KB
    __shared__ unsigned short SB[2 * BTS];     // 8 KB
    __shared__ unsigned short aggL[64 * AGP1]; // ~33 KB [node][feat]

    int tid = threadIdx.x;
    int lane = tid & 63;
    int wave = tid >> 6;
    int quad = lane >> 4, l16 = lane & 15;
    int wm = wave * 32;            // 8 waves cover 256 rows
    int sr = lane >> 2, sc = lane & 3;

    // ---------- stage 1: aggT (M=256 feats, N=64 nodes, K=512) ----------
    {
        f32x4 acc[2][4] = {};
        auto issue = [&](int g) {
            int kk = g << 5;
            unsigned short* Ad = SA + (g & 1) * ATS;
            int r = wave * 16 + sr;
            int c = sc ^ SWZ(r);
            async_ld16(HT + (long)r * Nn + kk + c * 8, Ad + (wave * 16) * 32);
            int r2 = 128 + r;
            int c2 = sc ^ SWZ(r2);
            async_ld16(HT + (long)r2 * Nn + kk + c2 * 8, Ad + (128 + wave * 16) * 32);
            if (wave < 4) {
                unsigned short* Bd = SB + (g & 1) * BTS;
                async_ld16(AR + (long)(n0g + r) * Nn + kk + c * 8,
                           Bd + (wave * 16) * 32);
            }
        };
        issue(0);
        for (int g = 0; g < 16; ++g) {
            __syncthreads();
            if (g + 1 < 16) issue(g + 1);
            const unsigned short* Ab = SA + (g & 1) * ATS;
            const unsigned short* Bb = SB + (g & 1) * BTS;
            bf16x8 af[2], bfr[4];
            #pragma unroll
            for (int i = 0; i < 2; ++i) {
                int r = wm + i * 16 + l16;
                af[i] = *(const bf16x8*)&Ab[r * 32 + (quad ^ SWZ(r)) * 8];
            }
            #pragma unroll
            for (int j = 0; j < 4; ++j) {
                int r = j * 16 + l16;
                bfr[j] = *(const bf16x8*)&Bb[r * 32 + (quad ^ SWZ(r)) * 8];
            }
            #pragma unroll
            for (int i = 0; i < 2; ++i)
                #pragma unroll
                for (int j = 0; j < 4; ++j)
                    acc[i][j] = __builtin_amdgcn_mfma_f32_16x16x32_bf16(
                        af[i], bfr[j], acc[i][j], 0, 0, 0);
        }
        // epilogue: feats = rows (4 consecutive), nodes = cols -> packed LDS store
        #pragma unroll
        for (int i = 0; i < 2; ++i) {
            int f = wm + i * 16 + quad * 4;
            #pragma unroll
            for (int j = 0; j < 4; ++j) {
                int nl = j * 16 + l16;
                f32x4 v = acc[i][j];
                ushort4v p;
                p[0] = f2bf(v[0]); p[1] = f2bf(v[1]);
                p[2] = f2bf(v[2]); p[3] = f2bf(v[3]);
                *(ushort4v*)&aggL[nl * AGP1 + f] = p;
            }
        }
    }
    __syncthreads();

    // ---------- stage 2: dense (M=256 outfeats, N=64 nodes, K=256+256) ----------
    f32x4 acc[2][4] = {};
    auto issue2 = [&](int g) {
        const unsigned short* Wp = (g < 8) ? WrelT1 : WrootT1;
        int kk = (g & 7) << 5;
        unsigned short* Ad = SA + (g & 1) * ATS;
        int r = wave * 16 + sr;
        int c = sc ^ SWZ(r);
        async_ld16(Wp + (long)r * Hh + kk + c * 8, Ad + (wave * 16) * 32);
        int r2 = 128 + r;
        int c2 = sc ^ SWZ(r2);
        async_ld16(Wp + (long)r2 * Hh + kk + c2 * 8, Ad + (128 + wave * 16) * 32);
        if (g >= 8 && wave < 4) {
            unsigned short* Bd = SB + (g & 1) * BTS;
            async_ld16(h1b + (nodeBase + r) * Hh + kk + c * 8, Bd + (wave * 16) * 32);
        }
    };
    issue2(0);
    for (int g = 0; g < 16; ++g) {
        __syncthreads();
        if (g + 1 < 16) issue2(g + 1);
        const unsigned short* Ab = SA + (g & 1) * ATS;
        bf16x8 af[2], bfr[4];
        #pragma unroll
        for (int i = 0; i < 2; ++i) {
            int r = wm + i * 16 + l16;
            af[i] = *(const bf16x8*)&Ab[r * 32 + (quad ^ SWZ(r)) * 8];
        }
        if (g < 8) {
            #pragma unroll
            for (int j = 0; j < 4; ++j) {
                int nl = j * 16 + l16;
                bfr[j] = *(const bf16x8*)&aggL[nl * AGP1 + (g << 5) + quad * 8];
            }
        } else {
            const unsigned short* Bb = SB + (g & 1) * BTS;
            #pragma unroll
            for (int j = 0; j < 4; ++j) {
                int r = j * 16 + l16;
                bfr[j] = *(const bf16x8*)&Bb[r * 32 + (quad ^ SWZ(r)) * 8];
            }
        }
        #pragma unroll
        for (int i = 0; i < 2; ++i)
            #pragma unroll
            for (int j = 0; j < 4; ++j)
                acc[i][j] = __builtin_amdgcn_mfma_f32_16x16x32_bf16(
                    af[i], bfr[j], acc[i][j], 0, 0, 0);
    }

    // pooled epilogue: each (wave,quad,i) owns unique feats lf..lf+3 -> direct stores
    #pragma unroll
    for (int i = 0; i < 2; ++i) {
        int lf = wm + i * 16 + quad * 4;
        float b0 = brel1[lf + 0], b1 = brel1[lf + 1];
        float b2 = brel1[lf + 2], b3 = brel1[lf + 3];
        float vp0 = 0.f, vp1 = 0.f, vp2 = 0.f, vp3 = 0.f;
        float mp0 = 0.f, mp1 = 0.f, mp2 = 0.f, mp3 = 0.f;
        #pragma unroll
        for (int j = 0; j < 4; ++j) {
            long node = nodeBase + j * 16 + l16;
            f32x4 v = acc[i][j];
            float o0 = fmaxf(v[0] + b0, 0.f), o1 = fmaxf(v[1] + b1, 0.f);
            float o2 = fmaxf(v[2] + b2, 0.f), o3 = fmaxf(v[3] + b3, 0.f);
            float h0v = bf2f(f2bf(o0)), h1v = bf2f(f2bf(o1));
            float h2v = bf2f(f2bf(o2)), h3v = bf2f(f2bf(o3));
            float wv = w[node];
            vp0 += wv * h0v; vp1 += wv * h1v; vp2 += wv * h2v; vp3 += wv * h3v;
            mp0 += h0v; mp1 += h1v; mp2 += h2v; mp3 += h3v;
        }
        #pragma unroll
        for (int m = 1; m < 16; m <<= 1) {
            vp0 += __shfl_xor(vp0, m); vp1 += __shfl_xor(vp1, m);
            vp2 += __shfl_xor(vp2, m); vp3 += __shfl_xor(vp3, m);
            mp0 += __shfl_xor(mp0, m); mp1 += __shfl_xor(mp1, m);
            mp2 += __shfl_xor(mp2, m); mp3 += __shfl_xor(mp3, m);
        }
        if (l16 == 0) {
            long o = ((long)(b * 8 + nt)) * Hh + lf;
            float4 vv = {vp0, vp1, vp2, vp3};
            float4 mm = {mp0, mp1, mp2, mp3};
            *(float4*)&vpart[o] = vv;
            *(float4*)&mpart[o] = mm;
        }
    }
}

// ---------------- prep: weight convert/transpose + w zero + h0 MFMA ------------
// blocks [0, 896): convert branch; blocks [896, 1152): h0 (m0 = (blk-896)*128)
__global__ __launch_bounds__(256) void prep_h0(
    const float* __restrict__ x, const float* __restrict__ Wg,
    const float* __restrict__ bg,
    const float* __restrict__ Wrel0, const float* __restrict__ Wroot0,
    const float* __restrict__ Wrel1, const float* __restrict__ Wroot1,
    unsigned short* __restrict__ T0, unsigned short* __restrict__ T1,
    unsigned short* __restrict__ T2, unsigned short* __restrict__ T3,
    float* __restrict__ w,
    unsigned short* __restrict__ h0b, unsigned short* __restrict__ h0T,
    float* __restrict__ sqv)
{
    if (blockIdx.x < 896) {
        int idx = blockIdx.x * 256 + threadIdx.x;    // 0..229375
        if (idx >= 196608) { w[idx - 196608] = 0.f; return; }    // w: 32768 floats
        const float* src; unsigned short* dst; int kin; int e;
        if      (idx <  32768) { src = Wrel0;  dst = T0; kin = 128; e = idx; }
        else if (idx <  65536) { src = Wroot0; dst = T1; kin = 128; e = idx - 32768; }
        else if (idx < 131072) { src = Wrel1;  dst = T2; kin = 256; e = idx - 65536; }
        else                   { src = Wroot1; dst = T3; kin = 256; e = idx - 131072; }
        int o = (kin == 128) ? (e >> 7) : (e >> 8);
        int i = e & (kin - 1);
        dst[e] = f2bf(src[(long)i * 256 + o]);       // conv out-dims are all 256
        return;
    }

    // ---- h0 branch: converts Wg on the fly ----
    __shared__ unsigned short As[128 * LDH];
    __shared__ unsigned short Bs[128 * LDH];
    __shared__ float rsq[128];

    int tid = threadIdx.x;
    int lane = tid & 63;
    int wave = tid >> 6;
    int quad = lane >> 4, l16 = lane & 15;
    int wm = (wave >> 1) * 64, wn = (wave & 1) * 64;
    int m0 = (blockIdx.x - 896) * 128;

    f32x4 acc[4][4] = {};

    for (int k0 = 0; k0 < Ff; k0 += 32) {
        __syncthreads();
        #pragma unroll
        for (int l = 0; l < 2; ++l) {
            int idx = tid + l * 256;
            int r = idx >> 2, ch = idx & 3;
            const float* px = x + (long)(m0 + r) * Ff + k0 + ch * 8;
            float4 xa = *(const float4*)px;
            float4 xb = *(const float4*)(px + 4);
            ushort4v pa, pb;
            pa[0] = f2bf(xa.x); pa[1] = f2bf(xa.y); pa[2] = f2bf(xa.z); pa[3] = f2bf(xa.w);
            pb[0] = f2bf(xb.x); pb[1] = f2bf(xb.y); pb[2] = f2bf(xb.z); pb[3] = f2bf(xb.w);
            *(ushort4v*)&As[r * LDH + ch * 8] = pa;
            *(ushort4v*)&As[r * LDH + ch * 8 + 4] = pb;
            int kk = k0 + ch * 8;
            ushort4v qa, qb;
            #pragma unroll
            for (int u = 0; u < 4; ++u) qa[u] = f2bf(Wg[(long)(kk + u) * 128 + r]);
            #pragma unroll
            for (int u = 0; u < 4; ++u) qb[u] = f2bf(Wg[(long)(kk + 4 + u) * 128 + r]);
            *(ushort4v*)&Bs[r * LDH + ch * 8] = qa;
            *(ushort4v*)&Bs[r * LDH + ch * 8 + 4] = qb;
        }
        __syncthreads();
        bf16x8 af[4], bfr[4];
        #pragma unroll
        for (int i = 0; i < 4; ++i)
            af[i] = *(const bf16x8*)&As[(wm + i * 16 + l16) * LDH + quad * 8];
        #pragma unroll
        for (int j = 0; j < 4; ++j)
            bfr[j] = *(const bf16x8*)&Bs[(wn + j * 16 + l16) * LDH + quad * 8];
        #pragma unroll
        for (int i = 0; i < 4; ++i)
            #pragma unroll
            for (int j = 0; j < 4; ++j)
                acc[i][j] = __builtin_amdgcn_mfma_f32_16x16x32_bf16(
                    af[i], bfr[j], acc[i][j], 0, 0, 0);
    }

    if (tid < 128) rsq[tid] = 0.f;
    __syncthreads();

    #pragma unroll
    for (int i = 0; i < 4; ++i) {
        int lrow = wm + i * 16 + quad * 4;
        int mb = m0 + lrow;
        float rp0 = 0.f, rp1 = 0.f, rp2 = 0.f, rp3 = 0.f;
        #pragma unroll
        for (int j = 0; j < 4; ++j) {
            int n = wn + j * 16 + l16;
            f32x4 v = acc[i][j];
            float bv = bg[n];
            unsigned short s0 = f2bf(v[0] + bv), s1 = f2bf(v[1] + bv);
            unsigned short s2 = f2bf(v[2] + bv), s3 = f2bf(v[3] + bv);
            h0b[(long)(mb + 0) * Ff + n] = s0;
            h0b[(long)(mb + 1) * Ff + n] = s1;
            h0b[(long)(mb + 2) * Ff + n] = s2;
            h0b[(long)(mb + 3) * Ff + n] = s3;
            ushort4v p; p[0] = s0; p[1] = s1; p[2] = s2; p[3] = s3;
            long ti = ((long)(mb >> 9) * Ff + n) * 512 + (mb & 511);
            *(ushort4v*)&h0T[ti] = p;
            float f0 = bf2f(s0), f1 = bf2f(s1), f2 = bf2f(s2), f3 = bf2f(s3);
            rp0 += f0 * f0; rp1 += f1 * f1; rp2 += f2 * f2; rp3 += f3 * f3;
        }
        #pragma unroll
        for (int m = 1; m < 16; m <<= 1) {
            rp0 += __shfl_xor(rp0, m);
            rp1 += __shfl_xor(rp1, m);
            rp2 += __shfl_xor(rp2, m);
            rp3 += __shfl_xor(rp3, m);
        }
        if (l16 == 0) {   // two waves share rows -> atomic
            atomicAdd(&rsq[lrow + 0], rp0);
            atomicAdd(&rsq[lrow + 1], rp1);
            atomicAdd(&rsq[lrow + 2], rp2);
            atomicAdd(&rsq[lrow + 3], rp3);
        }
    }
    __syncthreads();
    if (tid < 128) sqv[m0 + tid] = rsq[tid];
}

// ---------------- Gram -> adjacency A via MFMA (full tiles; packed T-store) -----
__global__ __launch_bounds__(512) void gram_A_mfma(
    const unsigned short* __restrict__ h0b, const float* __restrict__ sqv,
    const float* __restrict__ sigma, unsigned short* __restrict__ Aout,
    float* __restrict__ w)
{
    int id = blockIdx.x;
    int b = id & 63;
    int t = id >> 6;
    int i0 = (t & 3) * 128, j0 = (t >> 2) * 128;

    const unsigned short* H = h0b + (long)b * Nn * Ff;
    const float* SQ = sqv + (long)b * Nn;
    unsigned short* Ab = Aout + (long)b * Nn * Nn;

    __shared__ unsigned short Is[2 * TSZ];
    __shared__ unsigned short Js[2 * TSZ];
    __shared__ float rsum[128];

    int tid = threadIdx.x;
    int lane = tid & 63;
    int wave = tid >> 6;
    int quad = lane >> 4, l16 = lane & 15;
    int wm = (wave >> 1) * 32, wn = (wave & 1) * 64;

    int sr = lane >> 2, sc = lane & 3;

    f32x4 acc[2][4] = {};

    auto issue = [&](int g) {
        int kk = g << 5;
        unsigned short* Id = Is + (g & 1) * TSZ;
        unsigned short* Jd = Js + (g & 1) * TSZ;
        int r = wave * 16 + sr;
        int c = sc ^ SWZ(r);
        async_ld16(H + (long)(i0 + r) * Ff + kk + c * 8, Id + (wave * 16) * 32);
        async_ld16(H + (long)(j0 + r) * Ff + kk + c * 8, Jd + (wave * 16) * 32);
    };

    issue(0);
    for (int g = 0; g < (Ff >> 5); ++g) {
        __syncthreads();
        if (g + 1 < (Ff >> 5)) issue(g + 1);
        const unsigned short* Ib = Is + (g & 1) * TSZ;
        const unsigned short* Jb = Js + (g & 1) * TSZ;
        bf16x8 af[2], bfr[4];
        #pragma unroll
        for (int i = 0; i < 2; ++i) {
            int r = wm + i * 16 + l16;
            af[i] = *(const bf16x8*)&Ib[r * 32 + (quad ^ SWZ(r)) * 8];
        }
        #pragma unroll
        for (int j = 0; j < 4; ++j) {
            int r = wn + j * 16 + l16;
            bfr[j] = *(const bf16x8*)&Jb[r * 32 + (quad ^ SWZ(r)) * 8];
        }
        #pragma unroll
        for (int i = 0; i < 2; ++i)
            #pragma unroll
            for (int j = 0; j < 4; ++j)
                acc[i][j] = __builtin_amdgcn_mfma_f32_16x16x32_bf16(
                    af[i], bfr[j], acc[i][j], 0, 0, 0);
    }

    if (tid < 128) rsum[tid] = 0.f;
    __syncthreads();

    float s = sigma[0];
    float inv2s2 = 1.0f / (2.0f * s * s);
    #pragma unroll
    for (int i = 0; i < 2; ++i) {
        int lrow = wm + i * 16 + quad * 4;
        int rb = i0 + lrow;
        float rs0 = 0.f, rs1 = 0.f, rs2 = 0.f, rs3 = 0.f;
        #pragma unroll
        for (int j = 0; j < 4; ++j) {
            int c = j0 + wn + j * 16 + l16;
            float sqc = SQ[c];
            f32x4 v = acc[i][j];
            ushort4v pk;
            float av[4];
            #pragma unroll
            for (int r4 = 0; r4 < 4; ++r4) {
                int r = rb + r4;
                float d = fmaxf(SQ[r] + sqc - 2.0f * v[r4], 0.0f);
                unsigned short a = (r == c) ? (unsigned short)0
                                            : f2bf(__expf(-d * inv2s2));
                pk[r4] = a;
                av[r4] = bf2f(a);
            }
            *(ushort4v*)&Ab[(long)c * Nn + rb] = pk;
            rs0 += av[0]; rs1 += av[1]; rs2 += av[2]; rs3 += av[3];
        }
        #pragma unroll
        for (int m = 1; m < 16; m <<= 1) {
            rs0 += __shfl_xor(rs0, m);
            rs1 += __shfl_xor(rs1, m);
            rs2 += __shfl_xor(rs2, m);
            rs3 += __shfl_xor(rs3, m);
        }
        if (l16 == 0) {
            atomicAdd(&rsum[lrow + 0], rs0);
            atomicAdd(&rsum[lrow + 1], rs1);
            atomicAdd(&rsum[lrow + 2], rs2);
            atomicAdd(&rsum[lrow + 3], rs3);
        }
    }
    __syncthreads();
    if (tid < 128) atomicAdd(&w[(long)b * Nn + i0 + tid], rsum[tid]);
}

// ---------------- head: sum 8 nodeblock partials + layer2-collapse + mean + MLP ----
__global__ __launch_bounds__(256) void head_kernel(
    const float* __restrict__ vpart, const float* __restrict__ mpart,
    const float* __restrict__ Wrel2, const float* __restrict__ Wroot2,
    const float* __restrict__ brel2,
    const float* __restrict__ W1, const float* __restrict__ b1,
    const float* __restrict__ Wout, const float* __restrict__ bout,
    float* __restrict__ out)
{
    int b = blockIdx.x;
    int j = threadIdx.x;
    __shared__ float vs[Hh], ms[Hh], gs[Hh], g2[Hh];
    float vp = 0.f, mp = 0.f;
    #pragma unroll
    for (int p = 0; p < 8; ++p) {
        long o = ((long)(b * 8 + p)) * Hh + j;
        vp += vpart[o];
        mp += mpart[o];
    }
    vs[j] = vp * (1.0f / (float)Nn);
    ms[j] = mp * (1.0f / (float)Nn);
    __syncthreads();
    float s = brel2[j];
    for (int c = 0; c < Hh; ++c)
        s += vs[c] * Wrel2[c * Hh + j] + ms[c] * Wroot2[c * Hh + j];
    gs[j] = s;
    __syncthreads();
    float t = b1[j];
    for (int k = 0; k < Hh; ++k) t += gs[k] * W1[k * Hh + j];
    g2[j] = fmaxf(t, 0.f);
    __syncthreads();
    if (j < OUTD) {
        float s2 = bout[j];
        for (int k = 0; k < Hh; ++k) s2 += g2[k] * Wout[k * OUTD + j];
        out[b * OUTD + j] = s2;
    }
}

extern "C" void kernel_launch(void* const* d_in, const int* in_sizes, int n_in,
                              void* d_out, int out_size, void* d_ws, size_t ws_size,
                              hipStream_t stream) {
    const float* x      = (const float*)d_in[0];
    const float* sigma  = (const float*)d_in[4];
    const float* Wg     = (const float*)d_in[5];
    const float* bg     = (const float*)d_in[6];
    const float* Wrel0  = (const float*)d_in[7];
    const float* Wroot0 = (const float*)d_in[8];
    const float* brel0  = (const float*)d_in[9];
    const float* Wrel1  = (const float*)d_in[10];
    const float* Wroot1 = (const float*)d_in[11];
    const float* brel1  = (const float*)d_in[12];
    const float* Wrel2  = (const float*)d_in[13];
    const float* Wroot2 = (const float*)d_in[14];
    const float* brel2  = (const float*)d_in[15];
    const float* W1     = (const float*)d_in[16];
    const float* b1     = (const float*)d_in[17];
    const float* Wout   = (const float*)d_in[18];
    const float* bout   = (const float*)d_in[19];
    float* out = (float*)d_out;

    // Workspace layout (bytes)
    char* ws = (char*)d_ws;
    unsigned short* h0b  = (unsigned short*)(ws + 16777216);       // 8 MB
    unsigned short* h0T  = (unsigned short*)(ws + 25165824);       // 8 MB
    float*          sq   = (float*)(ws + 33554432);                // 128 KB
    unsigned short* Aadj = (unsigned short*)(ws + 33685504);       // 32 MB
    unsigned short* h1b  = (unsigned short*)(ws + 84017152);       // 16 MB
    unsigned short* h1T  = (unsigned short*)(ws + 100794368);      // 16 MB
    unsigned short* WrelT0  = (unsigned short*)(ws + 167903232);   // 64 KB
    unsigned short* WrootT0 = (unsigned short*)(ws + 167968768);   // 64 KB
    unsigned short* WrelT1  = (unsigned short*)(ws + 168034304);   // 128 KB
    unsigned short* WrootT1 = (unsigned short*)(ws + 168165376);   // 128 KB
    float*          w     = (float*)(ws + 168558592);              // 128 KB (A row sums)
    float*          vpart = (float*)(ws + 168689664);              // 512 KB
    float*          mpart = (float*)(ws + 169213952);              // 512 KB

    // prep (weights + w zero) and h0 in one dispatch
    prep_h0<<<1152, 256, 0, stream>>>(x, Wg, bg, Wrel0, Wroot0, Wrel1, Wroot1,
                                      WrelT0, WrootT0, WrelT1, WrootT1,
                                      w, h0b, h0T, sq);

    // A = exp(-dist/(2 sigma^2)), zero diag; row sums -> w (XCD-swizzled 1D)
    gram_A_mfma<<<dim3(16 * Bsz, 1, 1), 512, 0, stream>>>(h0b, sq, sigma, Aadj, w);

    // ---- layer 0: fused A@h + dense (agg via LDS) ----
    fused_l0<<<dim3(4 * Bsz, 1, 1), 512, 0, stream>>>(
        h0T, Aadj, h0b, WrelT0, WrootT0, brel0, h1b, h1T);

    // ---- layer 1 + dense + layer-2-collapse pooling, fully fused ----
    fused_l1<<<dim3(8 * Bsz, 1, 1), 512, 0, stream>>>(
        h1T, Aadj, h1b, WrelT1, WrootT1, brel1, w, vpart, mpart);

    // head (sum partials + layer-2 projection + mean + 2-layer MLP)
    head_kernel<<<Bsz, 256, 0, stream>>>(vpart, mpart, Wrel2, Wroot2, brel2,
                                         W1, b1, Wout, bout, out);
}